// Round 8
// baseline (131.831 us; speedup 1.0000x reference)
//
#include <hip/hip_runtime.h>

#define NN 384
#define CC 128
#define PP (NN*NN)      // 147456 positions
#define PB 128          // positions per block
#define NB (PP/PB)      // 1152 blocks
#define TPB 256         // 4 waves; each wave owns 32 rows (M=32 via 32x32x16 MFMA)

typedef __attribute__((ext_vector_type(8))) short bf16x8;
typedef __attribute__((ext_vector_type(16))) float f32x16;
typedef __attribute__((ext_vector_type(8))) unsigned short u16x8;

// weight planes in wfrag, 16384 ushorts (32KB) each
#define PL_APH 0
#define PL_AGH 1
#define PL_BPH 2
#define PL_BGH 3
#define PL_APL 4
#define PL_AGL 5
#define PL_BPL 6
#define PL_BGL 7
#define PL_G   8
#define PL_Z   9

// D-layout for 32x32: row = (reg&3) + 8*(reg>>2) + 4*h, col = lane&31 (m74/m101)
#define ROWT(reg,h) ((((reg)&3) + 8*((reg)>>2)) + 4*(h))

__device__ __forceinline__ unsigned short f2bf(float f){
  unsigned u = __float_as_uint(f);
  u += 0x7FFFu + ((u>>16)&1u);          // RNE
  return (unsigned short)(u>>16);
}
__device__ __forceinline__ float bf2f(unsigned h){
  return __uint_as_float(h<<16);
}
__device__ __forceinline__ unsigned pack2(float a, float b){
  return (unsigned)f2bf(a) | ((unsigned)f2bf(b)<<16);
}
__device__ __forceinline__ float sigmoidf_(float x){
  return __fdividef(1.0f, 1.0f + __expf(-x));
}

// ---------------------------------------------------------------------------
// K0: weights -> bf16 hi/lo planes in 32x32-MFMA B-fragment order:
// chunk (k0*4+n)*64+l holds W[n*32+(l&31)][k0*16+(l>>5)*8 .. +7], k0 in [0,8).
// ---------------------------------------------------------------------------
__global__ __launch_bounds__(256) void k0_wprep(
    const float* __restrict__ wap, const float* __restrict__ wag,
    const float* __restrict__ wbp, const float* __restrict__ wbg,
    const float* __restrict__ wg,  const float* __restrict__ wz,
    unsigned short* __restrict__ wfrag){
  int tid = blockIdx.x*256 + threadIdx.x;      // 0..20479
  int plane = tid >> 11;                       // 0..9
  int chunk = tid & 2047;
  int mat = (plane < 8) ? (plane & 3) : (plane == 8 ? 4 : 5);
  bool lo = (plane >= 4) && (plane < 8);
  const float* W = (mat==0)?wap:(mat==1)?wag:(mat==2)?wbp:(mat==3)?wbg:(mat==4)?wg:wz;
  int k0 = chunk >> 8, n = (chunk >> 6) & 3, l = chunk & 63;
  int o  = n*32 + (l & 31);
  int kb = k0*16 + ((l>>5)<<3);
  const float* s = W + o*128 + kb;
  u16x8 v;
  #pragma unroll
  for (int e=0;e<8;e++){
    float w = s[e];
    unsigned short h = f2bf(w);
    v[e] = lo ? f2bf(w - bf2f(h)) : h;
  }
  *(u16x8*)(wfrag + (size_t)tid*8) = v;
}

// ---------------------------------------------------------------------------
// Stage one 32KB plane into the LDS slot via global_load_lds (no staging VGPRs).
// ---------------------------------------------------------------------------
__device__ __forceinline__ void stage_plane(const unsigned short* __restrict__ g,
                                            unsigned char* slot, int t){
  int wv = t>>6, l = t&63;
  const unsigned char* src = (const unsigned char*)g + wv*8192 + l*16;
  unsigned char* dst = slot + wv*8192;
  #pragma unroll
  for (int i=0;i<8;i++)
    __builtin_amdgcn_global_load_lds(
        (const __attribute__((address_space(1))) unsigned int*)(src + i*1024),
        (__attribute__((address_space(3))) unsigned int*)(dst + i*1024),
        16, 0, 0);
}

// ---------------------------------------------------------------------------
// 32x32x16 MFMA passes. A-frag: row=row0+(l&31), k=k0*16+(l>>5)*8+e.
// Weight fragment at slot[(k0*4+n)*1024 + l*16] -> vaddr l*16 + imm offset.
// ---------------------------------------------------------------------------
__device__ __forceinline__ void pass_HL32(const bf16x8 aH[8], const bf16x8 aL[8],
    const unsigned char* w, int l, f32x16 acc[4]){
  #pragma unroll
  for (int k0=0;k0<8;k0++){
    #pragma unroll
    for (int n=0;n<4;n++){
      bf16x8 f = *(const bf16x8*)(w + (k0*4+n)*1024 + l*16);
      acc[n] = __builtin_amdgcn_mfma_f32_32x32x16_bf16(aH[k0], f, acc[n], 0,0,0);
      acc[n] = __builtin_amdgcn_mfma_f32_32x32x16_bf16(aL[k0], f, acc[n], 0,0,0);
    }
  }
}

__device__ __forceinline__ void pass_H32(const bf16x8 a[8],
    const unsigned char* w, int l, f32x16 acc[4]){
  #pragma unroll
  for (int k0=0;k0<8;k0++){
    #pragma unroll
    for (int n=0;n<4;n++){
      bf16x8 f = *(const bf16x8*)(w + (k0*4+n)*1024 + l*16);
      acc[n] = __builtin_amdgcn_mfma_f32_32x32x16_bf16(a[k0], f, acc[n], 0,0,0);
    }
  }
}

__device__ __forceinline__ void bias_init32(const float* __restrict__ b, int c,
                                            f32x16 acc[4]){
  #pragma unroll
  for (int n=0;n<4;n++){
    float v = b[n*32 + c];
    #pragma unroll
    for (int r=0;r<16;r++) acc[n][r] = v;
  }
}

// A-frag extraction from [row][col] swizzled bf16 tile at base (rows 0..127).
__device__ __forceinline__ void extract_frags(const unsigned char* base, int row0,
                                              int l, bf16x8 a[8]){
  int row = row0 + (l&31);
  int hh  = (l>>5)<<4;
  int swz = (row&7)<<4;
  #pragma unroll
  for (int k0=0;k0<8;k0++){
    unsigned off = (unsigned)(row*256 + (((k0<<5) + hh) ^ swz));
    a[k0] = *(const bf16x8*)(base + off);
  }
}

// ---------------------------------------------------------------------------
// Fused kernel, per 128-position tile; 4 waves, 32 rows each.
// LDS 64KB: R0[0,32K) = zn scratch -> xa(frag-order bf16) -> xn([row][col] bf16)
//           R1[32K,64K) = weight plane slot.
// ---------------------------------------------------------------------------
__global__ __launch_bounds__(TPB,2) void k_fused(
    const float* __restrict__ z, const float* __restrict__ mask,
    const float* __restrict__ bap, const float* __restrict__ bag,
    const float* __restrict__ bbp, const float* __restrict__ bbg,
    const float* __restrict__ bgg, const float* __restrict__ bz,
    const float* __restrict__ lniw, const float* __restrict__ lnib,
    const float* __restrict__ lnow, const float* __restrict__ lnob,
    const unsigned short* __restrict__ wfrag,
    float* __restrict__ out){
  __shared__ unsigned char lds[65536];
  unsigned char* R0 = lds;
  unsigned char* R1 = lds + 32768;
  const int t = threadIdx.x;
  const int pos0 = blockIdx.x * PB;
  const int rowg = t>>5, c4 = (t&31)<<2;

  // stage APH while P1 runs
  stage_plane(wfrag + PL_APH*16384, R1, t);

  // ---- P1: LN(z), two-pass var; keep normalized values in regs ----
  float4 nv[16];
  {
    float4 lw = *(const float4*)(lniw + c4);
    float4 lb = *(const float4*)(lnib + c4);
    #pragma unroll
    for (int it=0; it<16; ++it){
      int row = it*8 + rowg;
      float4 v = *(const float4*)(z + (size_t)(pos0+row)*CC + c4);
      float s = v.x+v.y+v.z+v.w;
      #pragma unroll
      for (int mm=1; mm<32; mm<<=1) s += __shfl_xor(s,mm);
      float mu = s*(1.0f/128.0f);
      float d0=v.x-mu, d1=v.y-mu, d2=v.z-mu, d3=v.w-mu;
      float ss = d0*d0+d1*d1+d2*d2+d3*d3;
      #pragma unroll
      for (int mm=1; mm<32; mm<<=1) ss += __shfl_xor(ss,mm);
      float rstd = rsqrtf(ss*(1.0f/128.0f) + 1e-5f);
      nv[it].x = d0*rstd*lw.x+lb.x; nv[it].y = d1*rstd*lw.y+lb.y;
      nv[it].z = d2*rstd*lw.z+lb.z; nv[it].w = d3*rstd*lw.w+lb.w;
      unsigned off = (unsigned)(row*256 + ((c4<<1) ^ ((row&7)<<4)));
      *(uint2*)(R0 + off) = make_uint2(pack2(nv[it].x, nv[it].y),
                                       pack2(nv[it].z, nv[it].w));
    }
  }
  __syncthreads();                       // znH visible; APH staged (vmcnt drained)

  const int wv = t>>6, l = t&63;
  const int c  = l&31;                   // D col-within-32 / A row-within-32
  const int h  = l>>5;
  const int row0 = wv*32;

  bf16x8 aH[8], aLo[8];
  extract_frags(R0, row0, l, aH);
  __syncthreads();                       // znH reads done
  // write znL (lo residual) into R0
  #pragma unroll
  for (int it=0; it<16; ++it){
    int row = it*8 + rowg;
    float l0 = nv[it].x - bf2f(f2bf(nv[it].x));
    float l1 = nv[it].y - bf2f(f2bf(nv[it].y));
    float l2 = nv[it].z - bf2f(f2bf(nv[it].z));
    float l3 = nv[it].w - bf2f(f2bf(nv[it].w));
    unsigned off = (unsigned)(row*256 + ((c4<<1) ^ ((row&7)<<4)));
    *(uint2*)(R0 + off) = make_uint2(pack2(l0,l1), pack2(l2,l3));
  }
  __syncthreads();                       // znL visible
  extract_frags(R0, row0, l, aLo);

  f32x16 accp[4], accg[4];

  // ---- a-phase ----
  bias_init32(bap, c, accp);
  pass_HL32(aH, aLo, R1, l, accp);                  // APH
  __syncthreads();
  stage_plane(wfrag + PL_AGH*16384, R1, t);
  __syncthreads();
  bias_init32(bag, c, accg);
  pass_HL32(aH, aLo, R1, l, accg);                  // AGH
  __syncthreads();
  stage_plane(wfrag + PL_APL*16384, R1, t);
  __syncthreads();
  pass_H32(aH, R1, l, accp);                        // APL
  __syncthreads();
  stage_plane(wfrag + PL_AGL*16384, R1, t);
  __syncthreads();
  pass_H32(aH, R1, l, accg);                        // AGL

  // xa = accp*sig(accg)*mask -> R0 wave-region, bf16 frag-order (conflict-free)
  {
    unsigned char* xr = R0 + wv*8192;
    #pragma unroll
    for (int n=0;n<4;n++){
      #pragma unroll
      for (int j=0;j<8;j++){
        float m0 = mask[pos0 + row0 + ROWT(2*j,   h)];
        float m1 = mask[pos0 + row0 + ROWT(2*j+1, h)];
        float a0 = accp[n][2*j]  *sigmoidf_(accg[n][2*j])  *m0;
        float a1 = accp[n][2*j+1]*sigmoidf_(accg[n][2*j+1])*m1;
        *(unsigned*)(xr + (n*8+j)*256 + l*4) = pack2(a0,a1);
      }
    }
  }
  __syncthreads();                       // AGL reads done
  stage_plane(wfrag + PL_BPH*16384, R1, t);
  __syncthreads();

  // ---- b-phase ----
  bias_init32(bbp, c, accp);
  pass_HL32(aH, aLo, R1, l, accp);                  // BPH
  __syncthreads();
  stage_plane(wfrag + PL_BGH*16384, R1, t);
  __syncthreads();
  bias_init32(bbg, c, accg);
  pass_HL32(aH, aLo, R1, l, accg);                  // BGH (last aLo use)
  __syncthreads();
  stage_plane(wfrag + PL_BPL*16384, R1, t);
  __syncthreads();
  pass_H32(aH, R1, l, accp);                        // BPL
  __syncthreads();
  stage_plane(wfrag + PL_BGL*16384, R1, t);
  __syncthreads();
  pass_H32(aH, R1, l, accg);                        // BGL

  // x = xa * (accp*sig(accg)*mask)  (readback own region)
  f32x16 xv[4];
  {
    const unsigned char* xr = R0 + wv*8192;
    #pragma unroll
    for (int n=0;n<4;n++){
      #pragma unroll
      for (int j=0;j<8;j++){
        float m0 = mask[pos0 + row0 + ROWT(2*j,   h)];
        float m1 = mask[pos0 + row0 + ROWT(2*j+1, h)];
        unsigned w = *(const unsigned*)(xr + (n*8+j)*256 + l*4);
        float b0 = accp[n][2*j]  *sigmoidf_(accg[n][2*j])  *m0;
        float b1 = accp[n][2*j+1]*sigmoidf_(accg[n][2*j+1])*m1;
        xv[n][2*j]   = bf2f(w & 0xffffu) * b0;
        xv[n][2*j+1] = bf2f(w >> 16)     * b1;
      }
    }
  }
  __syncthreads();                       // BGL reads done
  stage_plane(wfrag + PL_Z*16384, R1, t);  // overlaps LN below

  // ---- LN(x) in-register; rows live on 32-lane halves ----
  {
    float lw4[4], lb4[4];
    #pragma unroll
    for (int n=0;n<4;n++){ lw4[n]=lnow[n*32+c]; lb4[n]=lnob[n*32+c]; }
    #pragma unroll
    for (int reg=0; reg<16; ++reg){
      float s=0.f;
      #pragma unroll
      for (int n=0;n<4;n++) s += xv[n][reg];
      #pragma unroll
      for (int mm=1; mm<32; mm<<=1) s += __shfl_xor(s,mm);
      float mu = s*(1.0f/128.0f);
      float ss=0.f;
      #pragma unroll
      for (int n=0;n<4;n++){ float d = xv[n][reg]-mu; ss += d*d; }
      #pragma unroll
      for (int mm=1; mm<32; mm<<=1) ss += __shfl_xor(ss,mm);
      float rstd = rsqrtf(ss*(1.0f/128.0f) + 1e-5f);
      int row = row0 + ROWT(reg,h);
      int swz = (row&7)<<4;
      #pragma unroll
      for (int n=0;n<4;n++){
        int col = n*32 + c;
        float v = (xv[n][reg]-mu)*rstd*lw4[n]+lb4[n];
        *(unsigned short*)(R0 + row*256 + ((col<<1) ^ swz)) = f2bf(v);
      }
    }
  }
  // xn frags (wave-local rows; ds-ordered after our writes)
  bf16x8 a2[8];
  extract_frags(R0, row0, l, a2);
  __syncthreads();                       // Z staged (vmcnt drained)

  f32x16 o[4], gv[4];
  bias_init32(bz, c, o);
  pass_H32(a2, R1, l, o);                           // Z
  __syncthreads();
  stage_plane(wfrag + PL_G*16384, R1, t);
  __syncthreads();
  bias_init32(bgg, c, gv);
  pass_H32(aH, R1, l, gv);                          // G

  // ---- epilogue: out = o * sig(gv), direct coalesced scalar stores ----
  #pragma unroll
  for (int n=0;n<4;n++){
    #pragma unroll
    for (int reg=0; reg<16; ++reg){
      int row = row0 + ROWT(reg,h);
      out[(size_t)(pos0+row)*CC + n*32 + c] = o[n][reg]*sigmoidf_(gv[n][reg]);
    }
  }
}

extern "C" void kernel_launch(void* const* d_in, const int* in_sizes, int n_in,
                              void* d_out, int out_size, void* d_ws, size_t ws_size,
                              hipStream_t stream){
  const float* z     = (const float*)d_in[0];
  const float* mask  = (const float*)d_in[1];
  const float* w_ap  = (const float*)d_in[2];
  const float* b_ap  = (const float*)d_in[3];
  const float* w_bp  = (const float*)d_in[4];
  const float* b_bp  = (const float*)d_in[5];
  const float* w_ag  = (const float*)d_in[6];
  const float* b_ag  = (const float*)d_in[7];
  const float* w_bg  = (const float*)d_in[8];
  const float* b_bg  = (const float*)d_in[9];
  const float* w_g   = (const float*)d_in[10];
  const float* b_g   = (const float*)d_in[11];
  const float* w_z   = (const float*)d_in[12];
  const float* b_z   = (const float*)d_in[13];
  const float* ln_in_w  = (const float*)d_in[14];
  const float* ln_in_b  = (const float*)d_in[15];
  const float* ln_out_w = (const float*)d_in[16];
  const float* ln_out_b = (const float*)d_in[17];

  unsigned short* wfrag = (unsigned short*)d_ws;   // 10 planes * 32KB = 320KB

  k0_wprep<<<80, 256, 0, stream>>>(w_ap, w_ag, w_bp, w_bg, w_g, w_z, wfrag);
  k_fused<<<NB, TPB, 0, stream>>>(z, mask, b_ap, b_ag, b_bp, b_bg, b_g, b_z,
                                  ln_in_w, ln_in_b, ln_out_w, ln_out_b,
                                  wfrag, (float*)d_out);
}

// Round 10
// 126.973 us; speedup vs baseline: 1.0383x; 1.0383x over previous
//
#include <hip/hip_runtime.h>

#define NN 384
#define CC 128
#define PP (NN*NN)      // 147456 positions
#define PB 128          // positions per block
#define NB (PP/PB)      // 1152 blocks
#define TPB 256         // 4 waves; each wave owns 32 rows (32x32x16 MFMA)

typedef __attribute__((ext_vector_type(8))) short bf16x8;
typedef __attribute__((ext_vector_type(16))) float f32x16;
typedef __attribute__((ext_vector_type(8))) unsigned short u16x8;

// D-layout for 32x32: row = (reg&3) + 8*(reg>>2) + 4*h, col = lane&31 (m74/m101)
#define ROWT(reg,h) ((((reg)&3) + 8*((reg)>>2)) + 4*(h))

__device__ __forceinline__ unsigned short f2bf(float f){
  unsigned u = __float_as_uint(f);
  u += 0x7FFFu + ((u>>16)&1u);          // RNE
  return (unsigned short)(u>>16);
}
__device__ __forceinline__ float bf2f(unsigned h){ return __uint_as_float(h<<16); }
__device__ __forceinline__ unsigned pack2(float a, float b){
  return (unsigned)f2bf(a) | ((unsigned)f2bf(b)<<16);
}
__device__ __forceinline__ float sigmoidf_(float x){
  return __fdividef(1.0f, 1.0f + __expf(-x));
}

// ---------------------------------------------------------------------------
// K0: 10 bf16 planes in PHASE order:
// 0 APH, 1 AGH, 2 APL, 3 AGL, 4 BPH, 5 BGH, 6 BPL, 7 BGL, 8 Z, 9 G
// each in 32x32-MFMA B-fragment order: chunk (k0*4+n)*64+l holds
// W[n*32+(l&31)][k0*16+(l>>5)*8 .. +7], k0 in [0,8).
// ---------------------------------------------------------------------------
__global__ __launch_bounds__(256) void k0_wprep(
    const float* __restrict__ wap, const float* __restrict__ wag,
    const float* __restrict__ wbp, const float* __restrict__ wbg,
    const float* __restrict__ wg,  const float* __restrict__ wz,
    unsigned short* __restrict__ wfrag){
  int tid = blockIdx.x*256 + threadIdx.x;      // 0..20479
  int plane = tid >> 11, chunk = tid & 2047;
  const float* W = (plane==0||plane==2) ? wap
                 : (plane==1||plane==3) ? wag
                 : (plane==4||plane==6) ? wbp
                 : (plane==5||plane==7) ? wbg
                 : (plane==8) ? wz : wg;
  bool lo = (plane==2)||(plane==3)||(plane==6)||(plane==7);
  int k0 = chunk >> 8, n = (chunk >> 6) & 3, l = chunk & 63;
  int o  = n*32 + (l & 31);
  int kb = k0*16 + ((l>>5)<<3);
  const float* s = W + o*128 + kb;
  u16x8 v;
  #pragma unroll
  for (int e=0;e<8;e++){
    float w = s[e];
    unsigned short hh = f2bf(w);
    v[e] = lo ? f2bf(w - bf2f(hh)) : hh;
  }
  *(u16x8*)(wfrag + (size_t)tid*8) = v;
}

// ---------------------------------------------------------------------------
// Stage one 16KB half-plane into a slot via global_load_lds (linear copy).
// ---------------------------------------------------------------------------
__device__ __forceinline__ void stage_half(const unsigned char* __restrict__ src_base,
                                           unsigned char* slot, int t){
  int wv = t>>6, l = t&63;
  const unsigned char* src = src_base + wv*4096 + l*16;
  unsigned char* dst = slot + wv*4096;
  #pragma unroll
  for (int i=0;i<4;i++)
    __builtin_amdgcn_global_load_lds(
        (const __attribute__((address_space(1))) unsigned int*)(src + i*1024),
        (__attribute__((address_space(3))) unsigned int*)(dst + i*1024),
        16, 0, 0);
}

// ---------------------------------------------------------------------------
// Half-plane passes: 4 k-steps x 4 n. Slot chunk (kr*4+n)*1024 + l*16 holds
// k0 = kbase+kr. A-frag kbase selects a[kbase..kbase+3].
// ---------------------------------------------------------------------------
__device__ __forceinline__ void pass_H16(const bf16x8* a, int kbase,
    const unsigned char* slot, int l, f32x16* acc){
  #pragma unroll
  for (int kr=0;kr<4;kr++){
    #pragma unroll
    for (int n=0;n<4;n++){
      bf16x8 f = *(const bf16x8*)(slot + (kr*4+n)*1024 + l*16);
      acc[n] = __builtin_amdgcn_mfma_f32_32x32x16_bf16(a[kbase+kr], f, acc[n],0,0,0);
    }
  }
}
__device__ __forceinline__ void pass_HL16(const bf16x8* aH, const bf16x8* aL, int kbase,
    const unsigned char* slot, int l, f32x16* acc){
  #pragma unroll
  for (int kr=0;kr<4;kr++){
    #pragma unroll
    for (int n=0;n<4;n++){
      bf16x8 f = *(const bf16x8*)(slot + (kr*4+n)*1024 + l*16);
      acc[n] = __builtin_amdgcn_mfma_f32_32x32x16_bf16(aH[kbase+kr], f, acc[n],0,0,0);
      acc[n] = __builtin_amdgcn_mfma_f32_32x32x16_bf16(aL[kbase+kr], f, acc[n],0,0,0);
    }
  }
}
__device__ __forceinline__ void splat(const float* __restrict__ b, int c, f32x16* acc){
  #pragma unroll
  for (int n=0;n<4;n++){
    float v = b[n*32+c];
    #pragma unroll
    for (int r=0;r<16;r++) acc[n][r]=v;
  }
}
// A-frag extraction from [row][col] XOR-swizzled bf16 tile (R8-verified).
__device__ __forceinline__ void extract8(const unsigned char* R0, int row, int h,
                                         bf16x8 a[8]){
  int swz = (row&7)<<4;
  #pragma unroll
  for (int k0=0;k0<8;k0++){
    unsigned off = (unsigned)(row*256 + (((k0<<5) + (h<<4)) ^ swz));
    a[k0] = *(const bf16x8*)(R0 + off);
  }
}

// ---------------------------------------------------------------------------
// Fused kernel (R8 components + T3-minimum 2-slot half-plane pipeline).
// LDS 64KB: R0[0,32K) zn->xa->xn ; slots [32K,48K),[48K,64K). 2 blocks/CU.
// ---------------------------------------------------------------------------
__global__ __launch_bounds__(TPB,2) void k_fused(
    const float* __restrict__ z, const float* __restrict__ mask,
    const float* __restrict__ bap, const float* __restrict__ bag,
    const float* __restrict__ bbp, const float* __restrict__ bbg,
    const float* __restrict__ bgg, const float* __restrict__ bz,
    const float* __restrict__ lniw, const float* __restrict__ lnib,
    const float* __restrict__ lnow, const float* __restrict__ lnob,
    const unsigned short* __restrict__ wfrag,
    float* __restrict__ out){
  __shared__ unsigned char lds[65536];
  unsigned char* R0 = lds;
  const unsigned char* wfrag8 = (const unsigned char*)wfrag;
  const int t = threadIdx.x;
  const int pos0 = blockIdx.x * PB;
  const int rowg = t>>5, c4 = (t&31)<<2;

  // prologue: stage half-plane 0 -> slot 0 (drains at first barrier)
  stage_half(wfrag8, lds + 32768, t);

  // ---- P1: LN(z), two-pass var; znH -> R0; keep normalized f32 in nv (R8) ----
  float4 nv[16];
  {
    float4 lw = *(const float4*)(lniw + c4);
    float4 lb = *(const float4*)(lnib + c4);
    #pragma unroll
    for (int it=0; it<16; ++it){
      int row = it*8 + rowg;
      float4 v = *(const float4*)(z + (size_t)(pos0+row)*CC + c4);
      float s = v.x+v.y+v.z+v.w;
      #pragma unroll
      for (int mm=1; mm<32; mm<<=1) s += __shfl_xor(s,mm);
      float mu = s*(1.0f/128.0f);
      float d0=v.x-mu, d1=v.y-mu, d2=v.z-mu, d3=v.w-mu;
      float ss = d0*d0+d1*d1+d2*d2+d3*d3;
      #pragma unroll
      for (int mm=1; mm<32; mm<<=1) ss += __shfl_xor(ss,mm);
      float rstd = rsqrtf(ss*(1.0f/128.0f) + 1e-5f);
      nv[it].x = d0*rstd*lw.x+lb.x; nv[it].y = d1*rstd*lw.y+lb.y;
      nv[it].z = d2*rstd*lw.z+lb.z; nv[it].w = d3*rstd*lw.w+lb.w;
      unsigned off = (unsigned)(row*256 + ((c4<<1) ^ ((row&7)<<4)));
      *(uint2*)(R0 + off) = make_uint2(pack2(nv[it].x, nv[it].y),
                                       pack2(nv[it].z, nv[it].w));
    }
  }
  __syncthreads();

  const int wv = t>>6, l = t&63;
  const int c  = l&31, h = l>>5;
  const int row0 = wv*32;

  // ---- H->L swap with full barrier discipline (R8 verbatim) ----
  bf16x8 aH[8], aLo[8];
  extract8(R0, row0+c, h, aH);
  __syncthreads();
  #pragma unroll
  for (int it=0;it<16;++it){
    int row = it*8 + rowg;
    float l0 = nv[it].x - bf2f(f2bf(nv[it].x)), l1 = nv[it].y - bf2f(f2bf(nv[it].y));
    float l2 = nv[it].z - bf2f(f2bf(nv[it].z)), l3 = nv[it].w - bf2f(f2bf(nv[it].w));
    unsigned off = (unsigned)(row*256 + ((c4<<1) ^ ((row&7)<<4)));
    *(uint2*)(R0+off) = make_uint2(pack2(l0,l1), pack2(l2,l3));
  }
  __syncthreads();
  extract8(R0, row0+c, h, aLo);

  f32x16 accp[4], accg[4];
#define SL(p) (lds + 32768 + (((p)&1)<<14))
#define PH(p) do{ __syncthreads(); \
    if ((p)+1 < 20) stage_half(wfrag8 + ((size_t)((p)+1))*16384, SL((p)+1), t); }while(0)

  // ---- a: accp = bap + (aH+aLo)@WpH + aH@WpL ; accg likewise for gate ----
  PH(0);  splat(bap,c,accp); pass_HL16(aH,aLo,0,SL(0), l,accp);   // APH.0
  PH(1);  pass_HL16(aH,aLo,4,SL(1), l,accp);                      // APH.1
  PH(2);  splat(bag,c,accg); pass_HL16(aH,aLo,0,SL(2), l,accg);   // AGH.0
  PH(3);  pass_HL16(aH,aLo,4,SL(3), l,accg);                      // AGH.1
  PH(4);  pass_H16(aH,0,SL(4), l,accp);                           // APL.0
  PH(5);  pass_H16(aH,4,SL(5), l,accp);                           // APL.1
  PH(6);  pass_H16(aH,0,SL(6), l,accg);                           // AGL.0
  PH(7);  pass_H16(aH,4,SL(7), l,accg);                           // AGL.1
  // ---- xa = a*sig(ga)*mask -> park bf16 frag-order in own R0 region (R8) ----
  {
    unsigned char* xr = R0 + wv*8192;
    #pragma unroll
    for (int n=0;n<4;n++){
      #pragma unroll
      for (int j=0;j<8;j++){
        float m0 = mask[pos0+row0+ROWT(2*j,  h)];
        float m1 = mask[pos0+row0+ROWT(2*j+1,h)];
        float a0 = accp[n][2*j]  *sigmoidf_(accg[n][2*j])  *m0;
        float a1 = accp[n][2*j+1]*sigmoidf_(accg[n][2*j+1])*m1;
        *(unsigned*)(xr + (n*8+j)*256 + l*4) = pack2(a0,a1);
      }
    }
  }
  // ---- b ----
  PH(8);  splat(bbp,c,accp); pass_HL16(aH,aLo,0,SL(8), l,accp);   // BPH.0
  PH(9);  pass_HL16(aH,aLo,4,SL(9), l,accp);                      // BPH.1
  PH(10); splat(bbg,c,accg); pass_HL16(aH,aLo,0,SL(10),l,accg);   // BGH.0
  PH(11); pass_HL16(aH,aLo,4,SL(11),l,accg);                      // BGH.1 (last aLo)
  PH(12); pass_H16(aH,0,SL(12),l,accp);                           // BPL.0
  PH(13); pass_H16(aH,4,SL(13),l,accp);                           // BPL.1
  PH(14); pass_H16(aH,0,SL(14),l,accg);                           // BGL.0
  PH(15); pass_H16(aH,4,SL(15),l,accg);                           // BGL.1
  // ---- x = xa*b ; LN(x) ; xn -> R0 ; extract a2 (R8 verbatim, wave-local) ----
  bf16x8 a2[8];
  {
    f32x16 xv[4];
    const unsigned char* xr = R0 + wv*8192;
    #pragma unroll
    for (int n=0;n<4;n++){
      #pragma unroll
      for (int j=0;j<8;j++){
        float m0 = mask[pos0+row0+ROWT(2*j,  h)];
        float m1 = mask[pos0+row0+ROWT(2*j+1,h)];
        unsigned w = *(const unsigned*)(xr + (n*8+j)*256 + l*4);
        float b0 = accp[n][2*j]  *sigmoidf_(accg[n][2*j])  *m0;
        float b1 = accp[n][2*j+1]*sigmoidf_(accg[n][2*j+1])*m1;
        xv[n][2*j]   = bf2f(w & 0xffffu)*b0;
        xv[n][2*j+1] = bf2f(w >> 16)   *b1;
      }
    }
    float lw4[4], lb4[4];
    #pragma unroll
    for (int n=0;n<4;n++){ lw4[n]=lnow[n*32+c]; lb4[n]=lnob[n*32+c]; }
    #pragma unroll
    for (int reg=0; reg<16; ++reg){
      float s=0.f;
      #pragma unroll
      for (int n=0;n<4;n++) s += xv[n][reg];
      #pragma unroll
      for (int mm=1; mm<32; mm<<=1) s += __shfl_xor(s,mm);
      float mu = s*(1.0f/128.0f);
      float ss=0.f;
      #pragma unroll
      for (int n=0;n<4;n++){ float d=xv[n][reg]-mu; ss+=d*d; }
      #pragma unroll
      for (int mm=1; mm<32; mm<<=1) ss += __shfl_xor(ss,mm);
      float rstd = rsqrtf(ss*(1.0f/128.0f)+1e-5f);
      int row = row0 + ROWT(reg,h);
      int swz = (row&7)<<4;
      #pragma unroll
      for (int n=0;n<4;n++){
        int colb = (n*32+c)*2;
        float vvv = (xv[n][reg]-mu)*rstd*lw4[n]+lb4[n];
        *(unsigned short*)(R0 + row*256 + (colb ^ swz)) = f2bf(vvv);
      }
    }
    extract8(R0, row0+c, h, a2);   // wave-local rows; ds-ordered after our writes
  }
  // ---- final: o = xn@Wz+bz ; gv = zn@Wg+bgg ----
  PH(16); splat(bz,c,accp);  pass_H16(a2,0,SL(16),l,accp);        // Z.0
  PH(17); pass_H16(a2,4,SL(17),l,accp);                           // Z.1
  PH(18); splat(bgg,c,accg); pass_H16(aH,0,SL(18),l,accg);        // G.0
  PH(19); pass_H16(aH,4,SL(19),l,accg);                           // G.1
  // ---- epilogue: out = o * sig(gv) (R8 verbatim) ----
  #pragma unroll
  for (int n=0;n<4;n++){
    #pragma unroll
    for (int reg=0; reg<16; ++reg){
      int row = row0 + ROWT(reg,h);
      out[(size_t)(pos0+row)*CC + n*32 + c] = accp[n][reg]*sigmoidf_(accg[n][reg]);
    }
  }
#undef PH
#undef SL
}

extern "C" void kernel_launch(void* const* d_in, const int* in_sizes, int n_in,
                              void* d_out, int out_size, void* d_ws, size_t ws_size,
                              hipStream_t stream){
  const float* z     = (const float*)d_in[0];
  const float* mask  = (const float*)d_in[1];
  const float* w_ap  = (const float*)d_in[2];
  const float* b_ap  = (const float*)d_in[3];
  const float* w_bp  = (const float*)d_in[4];
  const float* b_bp  = (const float*)d_in[5];
  const float* w_ag  = (const float*)d_in[6];
  const float* b_ag  = (const float*)d_in[7];
  const float* w_bg  = (const float*)d_in[8];
  const float* b_bg  = (const float*)d_in[9];
  const float* w_g   = (const float*)d_in[10];
  const float* b_g   = (const float*)d_in[11];
  const float* w_z   = (const float*)d_in[12];
  const float* b_z   = (const float*)d_in[13];
  const float* ln_in_w  = (const float*)d_in[14];
  const float* ln_in_b  = (const float*)d_in[15];
  const float* ln_out_w = (const float*)d_in[16];
  const float* ln_out_b = (const float*)d_in[17];

  unsigned short* wfrag = (unsigned short*)d_ws;   // 10 planes * 32KB = 320KB

  k0_wprep<<<80, 256, 0, stream>>>(w_ap, w_ag, w_bp, w_bg, w_g, w_z, wfrag);
  k_fused<<<NB, TPB, 0, stream>>>(z, mask, b_ap, b_ag, b_bp, b_bg, b_g, b_z,
                                  ln_in_w, ln_in_b, ln_out_w, ln_out_b,
                                  wfrag, (float*)d_out);
}